// Round 6
// baseline (2949.473 us; speedup 1.0000x reference)
//
#include <hip/hip_runtime.h>
#include <hip/hip_bf16.h>

// Problem constants
constexpr int Bn   = 512;   // batch
constexpr int SK   = 128;   // K seq len (== BLOCK)
constexpr int SV   = 261;   // V seq len
constexpr int Dd   = 768;   // feature dim
constexpr int Hh   = 58;    // head dim for Q/K projections
constexpr int OUTn = 512;   // output dim of Vt
constexpr int IMG  = 197;
constexpr int Mrows = Bn * SV;               // 133632
constexpr long long CTX_ELEMS = (long long)Mrows * OUTn; // 68,419,584

// ws layout (bytes)
constexpr size_t WS_HOT = 0;        // 512 f32
constexpr size_t WS_WB  = 4096;     // 512*768 bf16

typedef __attribute__((ext_vector_type(8))) short short8;
typedef __attribute__((ext_vector_type(4))) float floatx4;

__device__ __forceinline__ short f2bf(float f) {
    return __builtin_bit_cast(short, __float2bfloat16(f));
}

__device__ __forceinline__ float sigmoidf_(float x) {
    return 1.0f / (1.0f + __expf(-x));
}

template <int N>
__device__ __forceinline__ void wait_vm() {
    asm volatile("s_waitcnt vmcnt(%0)" :: "n"(N) : "memory");
}

// ---------------- Kernel B: fused Qt/u/c + scores -> attn (out) + hot ----------------
__global__ void __launch_bounds__(512) scores_fused(
    const float* __restrict__ Q, const float* __restrict__ K,
    const float* __restrict__ Wq, const float* __restrict__ bq,
    const float* __restrict__ Wk, const float* __restrict__ bk,
    const float* __restrict__ Wsw, const float* __restrict__ bsw,
    float* __restrict__ attn_out, float* __restrict__ hot)
{
    int b = blockIdx.x;
    int t = threadIdx.x, lane = t & 63, w = t >> 6; // 8 waves

    __shared__ __align__(16) float qrow[Dd];
    __shared__ float qt[64];
    __shared__ __align__(16) float ul[Dd];
    __shared__ float al[SK];
    __shared__ float cbs;

    qrow[t] = Q[b * Dd + t];
    if (t < Dd - 512) qrow[t + 512] = Q[b * Dd + t + 512];
    __syncthreads();

    // qt[h] = Q[b]·Wq[h] + bq[h]
    for (int h = w; h < Hh; h += 8) {
        const float4* wr4 = (const float4*)(Wq + (size_t)h * Dd);
        const float4* q4  = (const float4*)qrow;
        float s = 0.f;
        #pragma unroll
        for (int j = 0; j < 3; ++j) {
            float4 a = q4[lane + 64 * j], c = wr4[lane + 64 * j];
            s += a.x * c.x + a.y * c.y + a.z * c.z + a.w * c.w;
        }
        #pragma unroll
        for (int off = 32; off; off >>= 1) s += __shfl_down(s, off);
        if (lane == 0) qt[h] = s + bq[h];
    }
    __syncthreads();

    // u[d] = sum_h qt[h]*Wk[h,d] ; c = qt·bk
    for (int d = t; d < Dd; d += 512) {
        float s = 0.f;
        #pragma unroll 2
        for (int h = 0; h < Hh; ++h) s += qt[h] * Wk[(size_t)h * Dd + d];
        ul[d] = s;
    }
    if (w == 0) {
        float v = (lane < Hh) ? qt[lane] * bk[lane] : 0.f;
        #pragma unroll
        for (int off = 32; off; off >>= 1) v += __shfl_down(v, off);
        if (lane == 0) cbs = v;
    }
    __syncthreads();

    float cb = cbs;
    const float4* Kb4 = (const float4*)(K + (size_t)b * SK * Dd);
    const float4* u4  = (const float4*)ul;
    for (int k = w; k < SK; k += 8) {
        const float4* kr4 = Kb4 + (size_t)k * (Dd / 4);
        float s = 0.f;
        #pragma unroll
        for (int j = 0; j < 3; ++j) {
            float4 a = kr4[lane + 64 * j], c = u4[lane + 64 * j];
            s += a.x * c.x + a.y * c.y + a.z * c.z + a.w * c.w;
        }
        #pragma unroll
        for (int off = 32; off; off >>= 1) s += __shfl_down(s, off);
        if (lane == 0) {
            float sc = (s + cb) * 0.0883883476483184f; // 1/sqrt(128)
            float a = sigmoidf_(sc);
            attn_out[(size_t)b * SK + k] = a;
            al[k] = a;
        }
    }
    __syncthreads();

    if (w == 0) {
        float v = al[lane] * Wsw[lane] + al[lane + 64] * Wsw[lane + 64];
        #pragma unroll
        for (int off = 32; off; off >>= 1) v += __shfl_down(v, off);
        if (lane == 0) hot[b] = sigmoidf_(v + bsw[0]);
    }
}

// ---------------- Kernel D: Wv f32 -> bf16, MFMA-fragment-major layout ----------------
// Chunk index = kb*32 + g (g = col>>4); within chunk lane = ((k>>3)&3)*16 + (col&15),
// 8 consecutive bf16 k's per lane -> fragment = one coalesced dwordx4 per wave.
__global__ void __launch_bounds__(256) wv_convert(
    const float* __restrict__ Wv, unsigned short* __restrict__ wsB)
{
    int t = blockIdx.x * 256 + threadIdx.x;
    if (t >= OUTn * Dd) return;
    int col = t / Dd;
    int k   = t - col * Dd;
    int kb = k >> 5, kgrp = (k >> 3) & 3, kj = k & 7;
    int g = col >> 4, cl = col & 15;
    size_t off = ((size_t)(kb * 32 + g) * 64 + (kgrp * 16 + cl)) * 8 + kj;
    wsB[off] = (unsigned short)f2bf(Wv[t]);
}

// ---------------- Kernel C: context = scale(b,s) * (V·Wv^T + bv) ----------------
// BM=64, BN=256, 4 waves (1m x 4n, wave tile 64x64). NO LDS, NO barriers:
// reg-staged A (f32) + B (bf16 fragments), fence-enforced double-buffering with
// counted vmcnt(12); consume-then-issue so the same buffer parity is reused.
// Latency hidden by occupancy (no LDS, ~190 VGPR -> target 6-8 blocks/CU).
__global__ void __launch_bounds__(256, 6) ctx_gemm(
    const float* __restrict__ V, const unsigned short* __restrict__ wsB,
    const float* __restrict__ bv, const float* __restrict__ hot,
    float* __restrict__ out)
{
    // XCD swizzle: 4176 blocks = 8 * 522; nt-pairs (same A rows) on one XCD.
    int bid = (blockIdx.x >> 3) + (blockIdx.x & 7) * 522;
    int nt = bid & 1;
    int mt = bid >> 1;
    int t = threadIdx.x, lane = t & 63, wn = t >> 6;
    int m_base = mt * 64;

    // A fragment rows: row = mr*16 + (lane&15), k-group = (lane>>4)*8 (8 consecutive f32)
    const float* arow[4];
    #pragma unroll
    for (int mr = 0; mr < 4; ++mr)
        arow[mr] = V + (size_t)(m_base + mr * 16 + (lane & 15)) * Dd + ((lane >> 4) * 8);

    const unsigned short* bB = wsB + ((size_t)(nt * 16 + wn * 4) * 64 + lane) * 8;

    floatx4 acc[4][4] = {};
    float4 pa[2][8];
    short8 pb[2][4];

// Issue one K-step's loads into buffer BUF (4 B dwordx4 + 8 A dwordx4).
#define LOADS(T, BUF)                                                              \
  {                                                                                \
    _Pragma("unroll")                                                              \
    for (int nr = 0; nr < 4; ++nr)                                                 \
      pb[BUF][nr] = *(const short8*)(bB + ((size_t)(T) * 32 + nr) * 512);          \
    _Pragma("unroll")                                                              \
    for (int mr = 0; mr < 4; ++mr) {                                               \
      pa[BUF][2 * mr]     = *(const float4*)(arow[mr] + (T) * 32);                 \
      pa[BUF][2 * mr + 1] = *(const float4*)(arow[mr] + (T) * 32 + 4);             \
    }                                                                              \
  }

    // Prologue: two steps in flight (24 outstanding vmem ops).
    LOADS(0, 0)
    __builtin_amdgcn_sched_barrier(0);
    LOADS(1, 1)
    __builtin_amdgcn_sched_barrier(0);

// Step T: wait vm(12) (retires step T's 12 ops, keeps T+1's 12 in flight) ->
// cvt+MFMA on buffer T&1 -> re-issue T+2 into the freed buffer T&1.
#define KSTEP(T, VM, DOLOAD)                                                       \
  {                                                                                \
    wait_vm<VM>();                                                                 \
    __builtin_amdgcn_sched_barrier(0);                                             \
    short8 af[4];                                                                  \
    _Pragma("unroll")                                                              \
    for (int mr = 0; mr < 4; ++mr) {                                               \
      float4 f0 = pa[(T) & 1][2 * mr], f1 = pa[(T) & 1][2 * mr + 1];               \
      af[mr][0] = f2bf(f0.x); af[mr][1] = f2bf(f0.y);                              \
      af[mr][2] = f2bf(f0.z); af[mr][3] = f2bf(f0.w);                              \
      af[mr][4] = f2bf(f1.x); af[mr][5] = f2bf(f1.y);                              \
      af[mr][6] = f2bf(f1.z); af[mr][7] = f2bf(f1.w);                              \
    }                                                                              \
    __builtin_amdgcn_s_setprio(1);                                                 \
    _Pragma("unroll")                                                              \
    for (int mr = 0; mr < 4; ++mr) {                                               \
      _Pragma("unroll")                                                            \
      for (int nr = 0; nr < 4; ++nr)                                               \
        acc[mr][nr] = __builtin_amdgcn_mfma_f32_16x16x32_bf16(af[mr],              \
                          pb[(T) & 1][nr], acc[mr][nr], 0, 0, 0);                  \
    }                                                                              \
    __builtin_amdgcn_s_setprio(0);                                                 \
    __builtin_amdgcn_sched_barrier(0);                                             \
    if (DOLOAD) { LOADS((T) + 2, (T) & 1) }                                        \
    __builtin_amdgcn_sched_barrier(0);                                             \
  }

    KSTEP(0,  12, 1)
    KSTEP(1,  12, 1)
    KSTEP(2,  12, 1)
    KSTEP(3,  12, 1)
    KSTEP(4,  12, 1)
    KSTEP(5,  12, 1)
    KSTEP(6,  12, 1)
    KSTEP(7,  12, 1)
    KSTEP(8,  12, 1)
    KSTEP(9,  12, 1)
    KSTEP(10, 12, 1)
    KSTEP(11, 12, 1)
    KSTEP(12, 12, 1)
    KSTEP(13, 12, 1)
    KSTEP(14, 12, 1)
    KSTEP(15, 12, 1)
    KSTEP(16, 12, 1)
    KSTEP(17, 12, 1)
    KSTEP(18, 12, 1)
    KSTEP(19, 12, 1)
    KSTEP(20, 12, 1)
    KSTEP(21, 12, 1)
    KSTEP(22, 12, 0)
    KSTEP(23, 0,  0)
#undef KSTEP
#undef LOADS

    // Epilogue: out[m,n] = scale(b,s) * (acc + bv[n]); C/D: col=lane&15, row=(lane>>4)*4+reg
    float bvv[4];
    #pragma unroll
    for (int nr = 0; nr < 4; ++nr)
        bvv[nr] = bv[nt * 256 + wn * 64 + nr * 16 + (lane & 15)];

    int ncol0 = nt * 256 + wn * 64 + (lane & 15);
    #pragma unroll
    for (int mr = 0; mr < 4; ++mr) {
        #pragma unroll
        for (int rg = 0; rg < 4; ++rg) {
            int m = m_base + mr * 16 + ((lane >> 4) << 2) + rg;
            int b = m / 261;
            int s = m - b * 261;
            float h = hot[b];
            float scale = (s < IMG) ? h : (1.0f - h);
            float* orow = out + (size_t)m * OUTn + ncol0;
            #pragma unroll
            for (int nr = 0; nr < 4; ++nr)
                orow[nr * 16] = scale * (acc[mr][nr][rg] + bvv[nr]);
        }
    }
}

extern "C" void kernel_launch(void* const* d_in, const int* in_sizes, int n_in,
                              void* d_out, int out_size, void* d_ws, size_t ws_size,
                              hipStream_t stream) {
    const float* Q   = (const float*)d_in[0];
    const float* K   = (const float*)d_in[1];
    const float* V   = (const float*)d_in[2];
    const float* Wq  = (const float*)d_in[3];
    const float* bq  = (const float*)d_in[4];
    const float* Wk  = (const float*)d_in[5];
    const float* bk  = (const float*)d_in[6];
    const float* Wsw = (const float*)d_in[7];
    const float* bsw = (const float*)d_in[8];
    const float* Wv  = (const float*)d_in[9];
    const float* bv  = (const float*)d_in[10];

    float* out = (float*)d_out;
    char* ws = (char*)d_ws;
    float* hot = (float*)(ws + WS_HOT);
    unsigned short* wsB = (unsigned short*)(ws + WS_WB);

    hipLaunchKernelGGL(wv_convert, dim3((OUTn * Dd + 255) / 256), dim3(256), 0, stream, Wv, wsB);
    hipLaunchKernelGGL(scores_fused, dim3(Bn), dim3(512), 0, stream,
                       Q, K, Wq, bq, Wk, bk, Wsw, bsw, out + CTX_ELEMS, hot);
    hipLaunchKernelGGL(ctx_gemm, dim3((Mrows / 64) * 2), dim3(256), 0, stream, V, wsB, bv, hot, out);
}

// Round 7
// 303.729 us; speedup vs baseline: 9.7109x; 9.7109x over previous
//
#include <hip/hip_runtime.h>
#include <hip/hip_bf16.h>

// Problem constants
constexpr int Bn   = 512;   // batch
constexpr int SK   = 128;   // K seq len (== BLOCK)
constexpr int SV   = 261;   // V seq len
constexpr int Dd   = 768;   // feature dim
constexpr int Hh   = 58;    // head dim for Q/K projections
constexpr int OUTn = 512;   // output dim of Vt
constexpr int IMG  = 197;
constexpr int Mrows = Bn * SV;               // 133632
constexpr long long CTX_ELEMS = (long long)Mrows * OUTn; // 68,419,584

// ws layout (bytes)
constexpr size_t WS_HOT = 0;        // 512 f32
constexpr size_t WS_WB  = 4096;     // 512*768 bf16

typedef __attribute__((ext_vector_type(8))) short short8;
typedef __attribute__((ext_vector_type(4))) float floatx4;

__device__ __forceinline__ short f2bf(float f) {
    return __builtin_bit_cast(short, __float2bfloat16(f));
}

__device__ __forceinline__ float sigmoidf_(float x) {
    return 1.0f / (1.0f + __expf(-x));
}

template <int N>
__device__ __forceinline__ void wait_vm() {
    asm volatile("s_waitcnt vmcnt(%0)" :: "n"(N) : "memory");
}

__device__ __forceinline__ void lds_dma16(const void* src, void* dst) {
    __builtin_amdgcn_global_load_lds(
        (const __attribute__((address_space(1))) void*)src,
        (__attribute__((address_space(3))) void*)dst,
        16, 0, 0);
}

// ---------------- Kernel B: fused Qt/u/c + scores -> attn (out) + hot ----------------
__global__ void __launch_bounds__(512) scores_fused(
    const float* __restrict__ Q, const float* __restrict__ K,
    const float* __restrict__ Wq, const float* __restrict__ bq,
    const float* __restrict__ Wk, const float* __restrict__ bk,
    const float* __restrict__ Wsw, const float* __restrict__ bsw,
    float* __restrict__ attn_out, float* __restrict__ hot)
{
    int b = blockIdx.x;
    int t = threadIdx.x, lane = t & 63, w = t >> 6; // 8 waves

    __shared__ __align__(16) float qrow[Dd];
    __shared__ float qt[64];
    __shared__ __align__(16) float ul[Dd];
    __shared__ float al[SK];
    __shared__ float cbs;

    qrow[t] = Q[b * Dd + t];
    if (t < Dd - 512) qrow[t + 512] = Q[b * Dd + t + 512];
    __syncthreads();

    // qt[h] = Q[b]·Wq[h] + bq[h]
    for (int h = w; h < Hh; h += 8) {
        const float4* wr4 = (const float4*)(Wq + (size_t)h * Dd);
        const float4* q4  = (const float4*)qrow;
        float s = 0.f;
        #pragma unroll
        for (int j = 0; j < 3; ++j) {
            float4 a = q4[lane + 64 * j], c = wr4[lane + 64 * j];
            s += a.x * c.x + a.y * c.y + a.z * c.z + a.w * c.w;
        }
        #pragma unroll
        for (int off = 32; off; off >>= 1) s += __shfl_down(s, off);
        if (lane == 0) qt[h] = s + bq[h];
    }
    __syncthreads();

    // u[d] = sum_h qt[h]*Wk[h,d] ; c = qt·bk
    for (int d = t; d < Dd; d += 512) {
        float s = 0.f;
        #pragma unroll 2
        for (int h = 0; h < Hh; ++h) s += qt[h] * Wk[(size_t)h * Dd + d];
        ul[d] = s;
    }
    if (w == 0) {
        float v = (lane < Hh) ? qt[lane] * bk[lane] : 0.f;
        #pragma unroll
        for (int off = 32; off; off >>= 1) v += __shfl_down(v, off);
        if (lane == 0) cbs = v;
    }
    __syncthreads();

    float cb = cbs;
    const float4* Kb4 = (const float4*)(K + (size_t)b * SK * Dd);
    const float4* u4  = (const float4*)ul;
    for (int k = w; k < SK; k += 8) {
        const float4* kr4 = Kb4 + (size_t)k * (Dd / 4);
        float s = 0.f;
        #pragma unroll
        for (int j = 0; j < 3; ++j) {
            float4 a = kr4[lane + 64 * j], c = u4[lane + 64 * j];
            s += a.x * c.x + a.y * c.y + a.z * c.z + a.w * c.w;
        }
        #pragma unroll
        for (int off = 32; off; off >>= 1) s += __shfl_down(s, off);
        if (lane == 0) {
            float sc = (s + cb) * 0.0883883476483184f; // 1/sqrt(128)
            float a = sigmoidf_(sc);
            attn_out[(size_t)b * SK + k] = a;
            al[k] = a;
        }
    }
    __syncthreads();

    if (w == 0) {
        float v = al[lane] * Wsw[lane] + al[lane + 64] * Wsw[lane + 64];
        #pragma unroll
        for (int off = 32; off; off >>= 1) v += __shfl_down(v, off);
        if (lane == 0) hot[b] = sigmoidf_(v + bsw[0]);
    }
}

// ---------------- Kernel D: Wv f32 -> bf16, MFMA-fragment-major layout ----------------
// Chunk index = kb*32 + g (g = col>>4); within chunk lane = ((k>>3)&3)*16 + (col&15),
// 8 consecutive bf16 k's per lane -> fragment = one contiguous 1KB block.
__global__ void __launch_bounds__(256) wv_convert(
    const float* __restrict__ Wv, unsigned short* __restrict__ wsB)
{
    int t = blockIdx.x * 256 + threadIdx.x;
    if (t >= OUTn * Dd) return;
    int col = t / Dd;
    int k   = t - col * Dd;
    int kb = k >> 5, kgrp = (k >> 3) & 3, kj = k & 7;
    int g = col >> 4, cl = col & 15;
    size_t off = ((size_t)(kb * 32 + g) * 64 + (kgrp * 16 + cl)) * 8 + kj;
    wsB[off] = (unsigned short)f2bf(Wv[t]);
}

// ---------------- Kernel C: context = scale(b,s) * (V·Wv^T + bv) ----------------
// BM=128, BN=256 (nt-pair), 512 thr = 8 waves (2m x 4n), wave tile 64x64.
// BOTH operands staged via global_load_lds DMA into double-buffered LDS
// (A 2x16KB granule-swizzled + B 2x16KB fragment-major). Stage-distance 2,
// two raw barriers per step, counted vmcnt(4) steady (never 0 mid-loop).
__global__ void __launch_bounds__(512, 4) ctx_gemm(
    const float* __restrict__ V, const unsigned short* __restrict__ wsB,
    const float* __restrict__ bv, const float* __restrict__ hot,
    float* __restrict__ out)
{
    // XCD swizzle: 2088 = 8*261; nt-pairs (2m,2m+1) land on the same XCD.
    int bx = blockIdx.x;
    int bid = (bx & 7) * 261 + (bx >> 3);
    int nt = bid & 1;
    int mt = bid >> 1;                    // 0..1043
    int t = threadIdx.x, lane = t & 63, w = t >> 6;
    int wm = w >> 2, wn = w & 3;          // 2 x 4 waves
    int m_base = mt * 128;

    __shared__ float          ldsA[2][4096];  // 2 x 16KB: 128 rows x 32 f32, swizzled
    __shared__ unsigned short ldsB[2][8192];  // 2 x 16KB: 16 frags x 512 u16

    // A DMA source (pre-swizzled): lane = r8*8 + c8 fetches logical granule c8^r8 of
    // row (w*16 + r8); LDS (linear write) then holds logical g at phys g^(row&7).
    int r8 = lane >> 3;
    int c8 = lane & 7;
    const float* srcA0 = V + (size_t)(m_base + w * 16 + r8) * Dd + (c8 ^ r8) * 4;
    const float* srcA1 = srcA0 + (size_t)8 * Dd;

    // B DMA source: contiguous 16KB chunk per (kb, nt); wave w copies 2KB.
    const unsigned short* srcB = wsB + (size_t)nt * 8192 + w * 1024 + lane * 8;

    // LDS read indices (float4 units): row*8 + (g ^ (row&7))
    int r0 = lane & 15;
    int g0 = (lane >> 4) * 2;
    int idxA0[4], idxA1[4];
    #pragma unroll
    for (int mr = 0; mr < 4; ++mr) {
        int row = wm * 64 + mr * 16 + r0;
        idxA0[mr] = row * 8 + (g0 ^ (row & 7));
        idxA1[mr] = row * 8 + ((g0 + 1) ^ (row & 7));
    }
    int idxB0 = (wn * 4) * 64 + lane;   // short8 units; frag stride 64

    floatx4 acc[4][4] = {};

#define STAGE(BUF, KB)                                                             \
  {                                                                                \
    lds_dma16(srcA0 + (size_t)(KB) * 32, &ldsA[BUF][w * 512]);                     \
    lds_dma16(srcA1 + (size_t)(KB) * 32, &ldsA[BUF][w * 512 + 256]);               \
    lds_dma16(srcB + (size_t)(KB) * 16384, &ldsB[BUF][w * 1024]);                  \
    lds_dma16(srcB + (size_t)(KB) * 16384 + 512, &ldsB[BUF][w * 1024 + 512]);      \
  }

    // Prologue: stage tiles 0,1. Queue [s0 x4, s1 x4] -> vm(4) retires s0.
    STAGE(0, 0)
    __builtin_amdgcn_sched_barrier(0);
    STAGE(1, 1)
    wait_vm<4>();
    __builtin_amdgcn_s_barrier();

// Step T: compute from buf T&1 | lgkm(0)+barrier#1 (reads done) |
// stage(T+2) into buf T&1 | vm(VM) retires s(T+1) | barrier#2.
#define KSTEP(T, VM, DOSTAGE, DOTAIL)                                              \
  {                                                                                \
    const float4* a4 = (const float4*)(&ldsA[(T) & 1][0]);                         \
    const short8* b8 = (const short8*)(&ldsB[(T) & 1][0]);                         \
    short8 af[4];                                                                  \
    _Pragma("unroll")                                                              \
    for (int mr = 0; mr < 4; ++mr) {                                               \
      float4 f0 = a4[idxA0[mr]];                                                   \
      float4 f1 = a4[idxA1[mr]];                                                   \
      af[mr][0] = f2bf(f0.x); af[mr][1] = f2bf(f0.y);                              \
      af[mr][2] = f2bf(f0.z); af[mr][3] = f2bf(f0.w);                              \
      af[mr][4] = f2bf(f1.x); af[mr][5] = f2bf(f1.y);                              \
      af[mr][6] = f2bf(f1.z); af[mr][7] = f2bf(f1.w);                              \
    }                                                                              \
    __builtin_amdgcn_s_setprio(1);                                                 \
    _Pragma("unroll")                                                              \
    for (int nr = 0; nr < 4; ++nr) {                                               \
      short8 pb = b8[idxB0 + nr * 64];                                             \
      _Pragma("unroll")                                                            \
      for (int mr = 0; mr < 4; ++mr)                                               \
        acc[mr][nr] = __builtin_amdgcn_mfma_f32_16x16x32_bf16(af[mr], pb,          \
                                                              acc[mr][nr], 0, 0, 0);\
    }                                                                              \
    __builtin_amdgcn_s_setprio(0);                                                 \
    if (!(DOTAIL)) {                                                               \
      __builtin_amdgcn_sched_barrier(0);                                           \
      asm volatile("s_waitcnt lgkmcnt(0)" ::: "memory");                           \
      __builtin_amdgcn_s_barrier(); /* #1: all waves done reading buf */           \
      __builtin_amdgcn_sched_barrier(0);                                           \
      if (DOSTAGE) STAGE((T) & 1, (T) + 2)                                         \
      __builtin_amdgcn_sched_barrier(0);                                           \
      wait_vm<VM>();                                                               \
      __builtin_amdgcn_s_barrier(); /* #2: next buffer staged for all waves */     \
    }                                                                              \
  }

    KSTEP(0,  4, 1, 0)
    KSTEP(1,  4, 1, 0)
    KSTEP(2,  4, 1, 0)
    KSTEP(3,  4, 1, 0)
    KSTEP(4,  4, 1, 0)
    KSTEP(5,  4, 1, 0)
    KSTEP(6,  4, 1, 0)
    KSTEP(7,  4, 1, 0)
    KSTEP(8,  4, 1, 0)
    KSTEP(9,  4, 1, 0)
    KSTEP(10, 4, 1, 0)
    KSTEP(11, 4, 1, 0)
    KSTEP(12, 4, 1, 0)
    KSTEP(13, 4, 1, 0)
    KSTEP(14, 4, 1, 0)
    KSTEP(15, 4, 1, 0)
    KSTEP(16, 4, 1, 0)
    KSTEP(17, 4, 1, 0)
    KSTEP(18, 4, 1, 0)
    KSTEP(19, 4, 1, 0)
    KSTEP(20, 4, 1, 0)
    KSTEP(21, 4, 1, 0)
    KSTEP(22, 0, 0, 0)   // retire s(23); no stage
    KSTEP(23, 0, 0, 1)   // tail: compute only
#undef KSTEP
#undef STAGE

    // Epilogue: out[m,n] = scale(b,s) * (acc + bv[n]); C/D: col=lane&15, row=(lane>>4)*4+reg
    float bvv[4];
    #pragma unroll
    for (int nr = 0; nr < 4; ++nr)
        bvv[nr] = bv[nt * 256 + wn * 64 + nr * 16 + (lane & 15)];

    int ncol0 = nt * 256 + wn * 64 + (lane & 15);
    #pragma unroll
    for (int mr = 0; mr < 4; ++mr) {
        #pragma unroll
        for (int rg = 0; rg < 4; ++rg) {
            int m = m_base + wm * 64 + mr * 16 + ((lane >> 4) << 2) + rg;
            int b = m / 261;
            int s = m - b * 261;
            float h = hot[b];
            float scale = (s < IMG) ? h : (1.0f - h);
            float* orow = out + (size_t)m * OUTn + ncol0;
            #pragma unroll
            for (int nr = 0; nr < 4; ++nr)
                orow[nr * 16] = scale * (acc[mr][nr][rg] + bvv[nr]);
        }
    }
}

extern "C" void kernel_launch(void* const* d_in, const int* in_sizes, int n_in,
                              void* d_out, int out_size, void* d_ws, size_t ws_size,
                              hipStream_t stream) {
    const float* Q   = (const float*)d_in[0];
    const float* K   = (const float*)d_in[1];
    const float* V   = (const float*)d_in[2];
    const float* Wq  = (const float*)d_in[3];
    const float* bq  = (const float*)d_in[4];
    const float* Wk  = (const float*)d_in[5];
    const float* bk  = (const float*)d_in[6];
    const float* Wsw = (const float*)d_in[7];
    const float* bsw = (const float*)d_in[8];
    const float* Wv  = (const float*)d_in[9];
    const float* bv  = (const float*)d_in[10];

    float* out = (float*)d_out;
    char* ws = (char*)d_ws;
    float* hot = (float*)(ws + WS_HOT);
    unsigned short* wsB = (unsigned short*)(ws + WS_WB);

    hipLaunchKernelGGL(wv_convert, dim3((OUTn * Dd + 255) / 256), dim3(256), 0, stream, Wv, wsB);
    hipLaunchKernelGGL(scores_fused, dim3(Bn), dim3(512), 0, stream,
                       Q, K, Wq, bq, Wk, bk, Wsw, bsw, out + CTX_ELEMS, hot);
    hipLaunchKernelGGL(ctx_gemm, dim3(Mrows / 128 * 2), dim3(512), 0, stream, V, wsB, bv, hot, out);
}